// Round 16
// baseline (295.263 us; speedup 1.0000x reference)
//
#include <hip/hip_runtime.h>
#include <hip/hip_bf16.h>

// QuaternionLinear = one 8192x4096x4096 GEMM vs Hamilton-assembled W.
// Round 16: 32x32x16 MFMA (2066 vs 2483 cyc/tile/CU floor) in R8's exact
// proven skeleton: compiler-generated ds_reads (R11/R12's identical 2.5e7
// "conflicts" with different layouts fingerprint the inline-asm read path,
// +4cyc/read uniform), 2-barrier merged window, counted VM(4), R4-proven
// 0-conflict content layout (slot s at row r = kslot s^(r&7)). Fragment &
// C/D layouts for 32x32x16 hardware-verified by R11/R12 absmax passes.

#define M_DIM 8192
#define N_DIM 4096
#define K_DIM 4096
#define BK 64
#define NT (K_DIM / BK)   // 64 K-tiles

typedef __attribute__((ext_vector_type(8))) short bf16x8;
typedef __attribute__((ext_vector_type(4))) float f32x4;
typedef __attribute__((ext_vector_type(16))) float f32x16;
typedef __attribute__((ext_vector_type(8))) unsigned short ushort8;

static __device__ __forceinline__ unsigned short f2bf(float f) {
    unsigned int u = __float_as_uint(f);
    return (unsigned short)((u + 0x7fffu + ((u >> 16) & 1u)) >> 16);
}
static __device__ __forceinline__ unsigned short f2bf_sgn(float f, unsigned int sg) {
    unsigned int u = __float_as_uint(f) ^ sg;
    return (unsigned short)((u + 0x7fffu + ((u >> 16) & 1u)) >> 16);
}

// ---------------- prep: x (fp32) -> xb (bf16 row-major) ----------------
__global__ __launch_bounds__(256) void cvt_x_kernel(const float* __restrict__ x,
                                                    unsigned short* __restrict__ xb) {
    int i = (blockIdx.x * 256 + threadIdx.x) * 8;
    f32x4 a = __builtin_nontemporal_load((const f32x4*)(x + i));
    f32x4 b = __builtin_nontemporal_load((const f32x4*)(x + i + 4));
    ushort8 o;
    o[0] = f2bf(a[0]); o[1] = f2bf(a[1]); o[2] = f2bf(a[2]); o[3] = f2bf(a[3]);
    o[4] = f2bf(b[0]); o[5] = f2bf(b[1]); o[6] = f2bf(b[2]); o[7] = f2bf(b[3]);
    *(ushort8*)(xb + i) = o;
}

// ---------------- prep: assemble Hamilton W (bf16 row-major) ----------------
__global__ __launch_bounds__(256) void prep_w_kernel(const float* __restrict__ Wr,
    const float* __restrict__ Wi, const float* __restrict__ Wj,
    const float* __restrict__ Wk, unsigned short* __restrict__ wb) {
    int row = blockIdx.x >> 1;
    int col = ((blockIdx.x & 1) * 256 + threadIdx.x) * 8;
    int p = row >> 10, q = col >> 10;
    int ci = p ^ q;
    const float* src = (ci == 0) ? Wr : (ci == 1) ? Wi : (ci == 2) ? Wj : Wk;
    unsigned int sg = ((0x428Eu >> (p * 4 + q)) & 1u) << 31;
    int so = (row & 1023) * 1024 + (col & 1023);
    f32x4 a = *(const f32x4*)(src + so);
    f32x4 b = *(const f32x4*)(src + so + 4);
    ushort8 o;
    o[0] = f2bf_sgn(a[0], sg); o[1] = f2bf_sgn(a[1], sg);
    o[2] = f2bf_sgn(a[2], sg); o[3] = f2bf_sgn(a[3], sg);
    o[4] = f2bf_sgn(b[0], sg); o[5] = f2bf_sgn(b[1], sg);
    o[6] = f2bf_sgn(b[2], sg); o[7] = f2bf_sgn(b[3], sg);
    *(ushort8*)(wb + row * 4096 + col) = o;
}

// ---------------- main GEMM ----------------
#define GLD16(gp, lp) __builtin_amdgcn_global_load_lds( \
    (const __attribute__((address_space(1))) void*)(gp), \
    (__attribute__((address_space(3))) void*)(lp), 16, 0, 0)

#define BAR() do { asm volatile("" ::: "memory"); \
                   __builtin_amdgcn_s_barrier(); \
                   asm volatile("" ::: "memory"); } while (0)
#define VM(n) asm volatile("s_waitcnt vmcnt(" #n ")" ::: "memory")

#define MF32(a, b, c) __builtin_amdgcn_mfma_f32_32x32x16_bf16(a, b, c, 0, 0, 0)

__global__ __launch_bounds__(512, 2) void qgemm_bf16(
    const unsigned short* __restrict__ A, const unsigned short* __restrict__ B,
    const float* __restrict__ bias, float* __restrict__ out)
{
    // [buf][A=0/B=1][half][128 rows][64 shorts] = 128 KiB.
    // Content: 16B slot s at row r holds kslot s^(r&7) (8 k-elems each) —
    // byte-identical to R4/R8 (0 conflicts measured with compiler reads).
    __shared__ __align__(16) unsigned short Lsh[2][2][2][128 * 64];

    int bid = blockIdx.x;
    int cpx = gridDim.x >> 3;                 // 512/8 = 64, bijective
    int wg  = (bid & 7) * cpx + (bid >> 3);
    int brow = (wg >> 4) * 256;               // 32 M-tiles
    int bcol = (wg & 15) * 256;               // 16 N-tiles

    int tid  = threadIdx.x;
    int lane = tid & 63;
    int wid  = tid >> 6;
    int hA   = wid >> 2;                      // wave's A half (128 rows)
    int wn   = wid & 3;                       // wave's 64-col B band
    int hB   = wn >> 1;
    int rB0  = (wn & 1) << 6;
    int l31  = lane & 31;
    int hi   = lane >> 5;

    const unsigned short* Ag = A + (size_t)brow * K_DIM;
    const unsigned short* Bg = B + (size_t)bcol * K_DIM;
    const char* LshB = (const char*)&Lsh[0][0][0][0];

    // 32x32x16 fragment reads (verified R11/R12): lane (l31,hi) of frag
    // (mi,kc) reads row = mi*32 + l31, kslot = 2*kc + hi -> byte slot =
    // (2kc+hi)^(l31&7). Decompose: bit4 = hi^(l31&1), bits5-6 = kc^((l31>>1)&3)
    // -> base + XOR(kc<<5) + imm mi*4096. buf toggle = ^0x10000.
    unsigned inrow = (((unsigned)hi ^ (unsigned)(l31 & 1)) << 4)
                   + (((unsigned)(l31 >> 1) & 3u) << 5);
    unsigned oA = (unsigned)(hA * 16384 + l31 * 128) + inrow;
    unsigned oB = 32768u + (unsigned)(hB * 16384 + (rB0 + l31) * 128) + inrow;

    f32x16 acc[4][2] = {};

    auto stage = [&](int buf, int ab, int half, int t) {
        const unsigned short* g = (ab ? Bg : Ag) + (size_t)(half << 7) * K_DIM + t * BK;
        unsigned short* l = &Lsh[buf][ab][half][0];
        #pragma unroll
        for (int i = 0; i < 2; ++i) {
            int c = i * 512 + tid;            // 16B chunk: row=c>>3, slot=c&7
            int r = c >> 3, s = c & 7;
            GLD16(g + (size_t)r * K_DIM + ((s ^ (r & 7)) << 3), l + (c << 3));
        }
    };
    auto RD = [&](unsigned off) -> bf16x8 {
        return *(const bf16x8*)(LshB + off);
    };

#define CLUST(kc) do { \
    __builtin_amdgcn_s_setprio(1); \
    acc[0][0] = MF32(aF##kc##0, bA[kc], acc[0][0]); \
    acc[0][1] = MF32(aF##kc##0, bB[kc], acc[0][1]); \
    acc[1][0] = MF32(aF##kc##1, bA[kc], acc[1][0]); \
    acc[1][1] = MF32(aF##kc##1, bB[kc], acc[1][1]); \
    acc[2][0] = MF32(aF##kc##2, bA[kc], acc[2][0]); \
    acc[2][1] = MF32(aF##kc##2, bB[kc], acc[2][1]); \
    acc[3][0] = MF32(aF##kc##3, bA[kc], acc[3][0]); \
    acc[3][1] = MF32(aF##kc##3, bB[kc], acc[3][1]); \
    __builtin_amdgcn_s_setprio(0); \
} while (0)

#define RDA(kc) \
    bf16x8 aF##kc##0 = RD((oA ^ ((unsigned)(kc) << 5))); \
    bf16x8 aF##kc##1 = RD((oA ^ ((unsigned)(kc) << 5)) + 4096u); \
    bf16x8 aF##kc##2 = RD((oA ^ ((unsigned)(kc) << 5)) + 8192u); \
    bf16x8 aF##kc##3 = RD((oA ^ ((unsigned)(kc) << 5)) + 12288u)

    // Prologue: tile0 A+B into buf0 (8 loads), tile1 B into buf1 (4 loads).
    stage(0, 0, 0, 0); stage(0, 0, 1, 0); stage(0, 1, 0, 0); stage(0, 1, 1, 0);
    stage(1, 1, 0, 1); stage(1, 1, 1, 1);
    VM(4); BAR();

    for (int t = 0; t < NT; ++t) {
        bf16x8 bA[4], bB[4];                  // B frags [kc], ni=0/1

        // ---- entry window: all B reads + A kc0; stage A(t+1); A kc1;
        //      MFMA kc0 ----
        #pragma unroll
        for (int kc = 0; kc < 4; ++kc) {
            unsigned ob = oB ^ ((unsigned)kc << 5);
            bA[kc] = RD(ob);
            bB[kc] = RD(ob + 4096u);
        }
        RDA(0);
        if (t + 1 < NT) { stage((t & 1) ^ 1, 0, 0, t + 1); stage((t & 1) ^ 1, 0, 1, t + 1); }
        RDA(1);
        CLUST(0);
        BAR();  // all waves consumed their B(t) reads -> B-region writable

        // ---- merged window: stage B(t+2); read-ahead + MFMA kc1..kc3 ----
        if (t + 2 < NT) { stage(t & 1, 1, 0, t + 2); stage(t & 1, 1, 1, t + 2); }
        RDA(2);
        CLUST(1);
        RDA(3);
        CLUST(2);
        CLUST(3);

        // Retire A(t+1)+B(t+1); leave the 4 newest (B(t+2)) in flight.
        if (t < NT - 2) { VM(4); } else { VM(0); }
        BAR();
        oA ^= 0x10000u; oB ^= 0x10000u;
    }
#undef CLUST
#undef RDA

    // epilogue: 32x32 C/D (verified m74/m101 + R11/R12): col = lane&31,
    // row = (reg&3) + 8*(reg>>2) + 4*(lane>>5).
    #pragma unroll
    for (int ni = 0; ni < 2; ++ni) {
        int col = bcol + wn * 64 + ni * 32 + l31;
        float bv = bias[col];
        #pragma unroll
        for (int mi = 0; mi < 4; ++mi) {
            int r0 = brow + hA * 128 + mi * 32 + 4 * hi;
            #pragma unroll
            for (int r = 0; r < 16; ++r) {
                int row = r0 + (r & 3) + 8 * (r >> 2);
                __builtin_nontemporal_store(acc[mi][ni][r] + bv,
                                            &out[(size_t)row * N_DIM + col]);
            }
        }
    }
}

// ---------------- fallback: reg-staged, no workspace (round-3, known-good) --
#define FBM 128
#define FBN 128
#define FBK 64
__global__ __launch_bounds__(256) void qgemm_fb(const float* __restrict__ x,
    const float* __restrict__ Wr, const float* __restrict__ Wi,
    const float* __restrict__ Wj, const float* __restrict__ Wk,
    const float* __restrict__ bias, float* __restrict__ out)
{
    __shared__ unsigned short As[FBM * FBK];
    __shared__ unsigned short Bs[FBN * FBK];

    int bid = blockIdx.x;
    int cpx = gridDim.x >> 3;
    int wg = (bid & 7) * cpx + (bid >> 3);
    int brow = (wg >> 5) * FBM;
    int bcol = (wg & 31) * FBN;

    int tid = threadIdx.x;
    int lane = tid & 63;
    int wv = tid >> 6;
    int wm = (wv >> 1) << 6;
    int wn = (wv & 1) << 6;
    int fr = lane & 15;
    int fk = (lane >> 4) << 3;

    int p = bcol >> 10;
    f32x4 acc[4][4] = {};

    for (int kt = 0; kt < K_DIM / FBK; ++kt) {
        int k0 = kt * FBK;
        int q = k0 >> 10;
        int ci = p ^ q;
        const float* wsrc = (ci == 0) ? Wr : (ci == 1) ? Wi : (ci == 2) ? Wj : Wk;
        unsigned int sg = ((0x428Eu >> (p * 4 + q)) & 1u) << 31;

        __syncthreads();
        #pragma unroll
        for (int i = 0; i < 4; ++i) {
            int c = i * 256 + tid;
            int row = c >> 3, colo = (c & 7) << 3;
            const float* s = x + (size_t)(brow + row) * K_DIM + k0 + colo;
            float4 a = *(const float4*)s;
            float4 b = *(const float4*)(s + 4);
            ushort8 o;
            o[0] = f2bf(a.x); o[1] = f2bf(a.y); o[2] = f2bf(a.z); o[3] = f2bf(a.w);
            o[4] = f2bf(b.x); o[5] = f2bf(b.y); o[6] = f2bf(b.z); o[7] = f2bf(b.w);
            *(ushort8*)(&As[c << 3]) = o;
        }
        #pragma unroll
        for (int i = 0; i < 4; ++i) {
            int c = i * 256 + tid;
            int row = c >> 3, colo = (c & 7) << 3;
            const float* s = wsrc + ((bcol + row) & 1023) * 1024 + ((k0 + colo) & 1023);
            float4 a = *(const float4*)s;
            float4 b = *(const float4*)(s + 4);
            ushort8 o;
            o[0] = f2bf_sgn(a.x, sg); o[1] = f2bf_sgn(a.y, sg);
            o[2] = f2bf_sgn(a.z, sg); o[3] = f2bf_sgn(a.w, sg);
            o[4] = f2bf_sgn(b.x, sg); o[5] = f2bf_sgn(b.y, sg);
            o[6] = f2bf_sgn(b.z, sg); o[7] = f2bf_sgn(b.w, sg);
            *(ushort8*)(&Bs[c << 3]) = o;
        }
        __syncthreads();

        #pragma unroll
        for (int ks = 0; ks < 2; ++ks) {
            bf16x8 af[4], bfr[4];
            #pragma unroll
            for (int m = 0; m < 4; ++m)
                af[m] = *(const bf16x8*)(&As[(wm + m * 16 + fr) * FBK + ks * 32 + fk]);
            #pragma unroll
            for (int n = 0; n < 4; ++n)
                bfr[n] = *(const bf16x8*)(&Bs[(wn + n * 16 + fr) * FBK + ks * 32 + fk]);
            #pragma unroll
            for (int m = 0; m < 4; ++m)
                #pragma unroll
                for (int n = 0; n < 4; ++n)
                    acc[m][n] = __builtin_amdgcn_mfma_f32_16x16x32_bf16(
                        af[m], bfr[n], acc[m][n], 0, 0, 0);
        }
    }

    int cr = (lane >> 4) << 2;
    int cc = lane & 15;
    #pragma unroll
    for (int n = 0; n < 4; ++n) {
        int col = bcol + wn + n * 16 + cc;
        float bv = bias[col];
        #pragma unroll
        for (int m = 0; m < 4; ++m) {
            int r0 = brow + wm + m * 16 + cr;
            #pragma unroll
            for (int r = 0; r < 4; ++r)
                out[(size_t)(r0 + r) * N_DIM + col] = acc[m][n][r] + bv;
        }
    }
}

extern "C" void kernel_launch(void* const* d_in, const int* in_sizes, int n_in,
                              void* d_out, int out_size, void* d_ws, size_t ws_size,
                              hipStream_t stream) {
    const float* x    = (const float*)d_in[0];
    const float* Wr   = (const float*)d_in[1];
    const float* Wi   = (const float*)d_in[2];
    const float* Wj   = (const float*)d_in[3];
    const float* Wk   = (const float*)d_in[4];
    const float* bias = (const float*)d_in[5];
    float* out = (float*)d_out;

    const size_t xb_bytes = (size_t)M_DIM * K_DIM * 2;  // 64 MiB
    const size_t wb_bytes = (size_t)N_DIM * K_DIM * 2;  // 32 MiB

    if (ws_size >= xb_bytes + wb_bytes) {
        unsigned short* xb = (unsigned short*)d_ws;
        unsigned short* wb = (unsigned short*)((char*)d_ws + xb_bytes);
        cvt_x_kernel<<<(M_DIM * K_DIM) / 2048, 256, 0, stream>>>(x, xb);
        prep_w_kernel<<<N_DIM * 2, 256, 0, stream>>>(Wr, Wi, Wj, Wk, wb);
        const int n_blocks = (M_DIM / 256) * (N_DIM / 256);  // 512
        qgemm_bf16<<<n_blocks, 512, 0, stream>>>(xb, wb, bias, out);
    } else {
        const int n_blocks = (M_DIM / FBM) * (N_DIM / FBN);  // 2048
        qgemm_fb<<<n_blocks, 256, 0, stream>>>(x, Wr, Wi, Wj, Wk, bias, out);
    }
}